// Round 7
// baseline (44.223 us; speedup 1.0000x reference)
//
#include <hip/hip_runtime.h>
#include <hip/hip_bf16.h>

typedef __attribute__((ext_vector_type(8))) short bf16x8;
typedef __attribute__((ext_vector_type(4))) float f32x4;
typedef __attribute__((ext_vector_type(4))) unsigned int u32x4;

#define DD 1024
#define KC 256
#define BM 64
#define BN 128
#define BK 64
#define KSTEPS (DD / BK)      // 16
#define ABYTES 8192           // A region per buffer (64x64 bf16)
#define BBYTES 16384          // B region per buffer (128x64 bf16)
#define BUF_BYTES (ABYTES + BBYTES)   // 24 KB; x2 = 48 KB -> 3 blocks/CU
#define CLAMP_EPS 1e-8f

__device__ __forceinline__ unsigned short f2bf(float f) {
  unsigned int u = __float_as_uint(f);
  u += 0x7FFFu + ((u >> 16) & 1u);   // RNE
  return (unsigned short)(u >> 16);
}

__device__ __forceinline__ unsigned int pk2(float x, float y) {
  __hip_bfloat162 h = __float22bfloat162_rn(float2{x, y});
  return *reinterpret_cast<unsigned int*>(&h);
}

__device__ __forceinline__ bf16x8 cvt8(f32x4 lo, f32x4 hi) {
  u32x4 w;
  w[0] = pk2(lo[0], lo[1]);
  w[1] = pk2(lo[2], lo[3]);
  w[2] = pk2(hi[0], hi[1]);
  w[3] = pk2(hi[2], hi[3]);
  return __builtin_bit_cast(bf16x8, w);
}

// async global->LDS, 16B per lane; LDS dest is wave-uniform base + lane*16
__device__ __forceinline__ void gload_lds16(const short* g, short* l) {
  __builtin_amdgcn_global_load_lds(
      (__attribute__((address_space(1))) void*)g,
      (__attribute__((address_space(3))) void*)l, 16, 0, 0);
}

// Kernel 1: per-center inverse-norm + prenormalized bf16 copy into ws.
__global__ __launch_bounds__(64) void center_norm_kernel(
    const float* __restrict__ c, short* __restrict__ cn) {
  const int k = blockIdx.x;
  const int lane = threadIdx.x;
  const float* row = c + (size_t)k * DD + lane * 16;
  f32x4 v0 = *(const f32x4*)(row);
  f32x4 v1 = *(const f32x4*)(row + 4);
  f32x4 v2 = *(const f32x4*)(row + 8);
  f32x4 v3 = *(const f32x4*)(row + 12);
  float ss = 0.f;
  #pragma unroll
  for (int j = 0; j < 4; ++j)
    ss += v0[j]*v0[j] + v1[j]*v1[j] + v2[j]*v2[j] + v3[j]*v3[j];
  #pragma unroll
  for (int off = 32; off > 0; off >>= 1) ss += __shfl_xor(ss, off, 64);
  const float inv = 1.f / fmaxf(sqrtf(ss), CLAMP_EPS);
  bf16x8 lo, hi;
  #pragma unroll
  for (int j = 0; j < 4; ++j) {
    lo[j]     = (short)f2bf(v0[j] * inv);
    lo[j + 4] = (short)f2bf(v1[j] * inv);
    hi[j]     = (short)f2bf(v2[j] * inv);
    hi[j + 4] = (short)f2bf(v3[j] * inv);
  }
  short* o = cn + (size_t)k * DD + lane * 16;
  *(bf16x8*)o = lo;
  *(bf16x8*)(o + 8) = hi;
}

// Kernel 2: fused cosine-sim GEMM, R3 sync structure (proven 37.4us),
// retiled to BM=64 x BN=128, 48KB LDS -> 3 blocks/CU, grid 1024.
// Chunked XCD swizzle puts the two N-half blocks of a row-stripe on the
// same XCD 8 dispatch slots apart -> 2nd x-read hits XCD-L2.
__global__ __launch_bounds__(512, 6) void cossim_gemm_kernel(
    const float* __restrict__ x, const short* __restrict__ cn,
    float* __restrict__ out) {
  __shared__ __align__(16) char lds_raw[2 * BUF_BYTES];   // 48 KB

  const int t = threadIdx.x;
  const int lane = t & 63;
  const int wid = t >> 6;
  const int wm = wid >> 2;     // 0..1 -> 32-row slab
  const int wn = wid & 3;      // 0..3 -> 32-col slab
  const int fr = lane & 15;

  // chunked XCD swizzle (bijective: 1024 % 8 == 0)
  const int nwg = gridDim.x;                    // 1024
  const int lb = (blockIdx.x & 7) * (nwg >> 3) + (blockIdx.x >> 3);
  const int row0 = (lb >> 1) * BM;
  const int col0 = (lb & 1) * BN;

  // ---- A staging geometry: thread owns (row ar, 8-float segment aseg)
  const int ar = t >> 3;
  const int aseg = t & 7;
  const float* aptr = x + (size_t)(row0 + ar) * DD + aseg * 8;
  const int sA = (ar * BK + aseg * 8) ^ ((ar & 7) << 3);   // swizzled, shorts

  // ---- B staging via gload_lds: pre-swizzled source, linear LDS dest.
  // 128 rows x 64 cols bf16 = 16KB = 1024 chunks of 8 shorts; 2 per thread.
  const short* bsrc0; const short* bsrc1;
  int bld0, bld1;
  {
    #define BGEO(i, PS, PL) {                       \
      const int g = (wid * 2 + (i)) * 64 + lane;    \
      const int n = g >> 3;                         \
      const int cp = (g & 7) ^ (n & 7);             \
      PS = cn + (size_t)(col0 + n) * DD + cp * 8;   \
      PL = (wid * 2 + (i)) * 512; }
    BGEO(0, bsrc0, bld0) BGEO(1, bsrc1, bld1)
    #undef BGEO
  }

  float ssq = 0.f;

  // ---- prologue: stage tile 0 into buffer 0, prefetch A tile 1
  f32x4 rA0 = *(const f32x4*)(aptr);
  f32x4 rA1 = *(const f32x4*)(aptr + 4);
  {
    short* bsb = (short*)(lds_raw + ABYTES);
    gload_lds16(bsrc0, bsb + bld0);
    gload_lds16(bsrc1, bsb + bld1);
  }
  #pragma unroll
  for (int j = 0; j < 4; ++j) {
    ssq = fmaf(rA0[j], rA0[j], ssq);
    ssq = fmaf(rA1[j], rA1[j], ssq);
  }
  *(bf16x8*)&((short*)lds_raw)[sA] = cvt8(rA0, rA1);
  rA0 = *(const f32x4*)(aptr + BK);
  rA1 = *(const f32x4*)(aptr + BK + 4);
  __syncthreads();

  f32x4 acc[2][2];
  #pragma unroll
  for (int i = 0; i < 2; ++i)
    #pragma unroll
    for (int j = 0; j < 2; ++j) acc[i][j] = (f32x4)(0.f);

  #pragma unroll
  for (int ks = 0; ks < KSTEPS; ++ks) {
    const int cb = ks & 1;
    const int nb = cb ^ 1;
    // ---- 1. issue B gloads for tile ks+1 (R3 order, proven)
    if (ks + 1 < KSTEPS) {
      short* bsb = (short*)(lds_raw + nb * BUF_BYTES + ABYTES);
      gload_lds16(bsrc0 + (ks + 1) * BK, bsb + bld0);
      gload_lds16(bsrc1 + (ks + 1) * BK, bsb + bld1);
    }
    // ---- 2. issue A reg loads for tile ks+2 (spans this window's barrier)
    f32x4 pA0, pA1;
    if (ks + 2 < KSTEPS) {
      pA0 = *(const f32x4*)(aptr + (ks + 2) * BK);
      pA1 = *(const f32x4*)(aptr + (ks + 2) * BK + 4);
    }
    // ---- 3. ssq + cvt + ds_write of tile ks+1 from regs
    if (ks + 1 < KSTEPS) {
      #pragma unroll
      for (int j = 0; j < 4; ++j) {
        ssq = fmaf(rA0[j], rA0[j], ssq);
        ssq = fmaf(rA1[j], rA1[j], ssq);
      }
      short* asb = (short*)(lds_raw + nb * BUF_BYTES);
      *(bf16x8*)&asb[sA] = cvt8(rA0, rA1);
    }
    // ---- 4. compute tile ks from buffer cb
    {
      const short* asb = (const short*)(lds_raw + cb * BUF_BYTES);
      const short* bsb = (const short*)(lds_raw + cb * BUF_BYTES + ABYTES);
      const int swz = (fr & 7) << 3;
      #pragma unroll
      for (int ksub = 0; ksub < 2; ++ksub) {
        const int kk = ksub * 32 + (lane >> 4) * 8;
        bf16x8 af0 = *(const bf16x8*)&asb[((wm * 32 + fr) * BK + kk) ^ swz];
        bf16x8 af1 = *(const bf16x8*)&asb[((wm * 32 + 16 + fr) * BK + kk) ^ swz];
        bf16x8 bf0 = *(const bf16x8*)&bsb[((wn * 32 + fr) * BK + kk) ^ swz];
        bf16x8 bf1 = *(const bf16x8*)&bsb[((wn * 32 + 16 + fr) * BK + kk) ^ swz];
        acc[0][0] = __builtin_amdgcn_mfma_f32_16x16x32_bf16(af0, bf0, acc[0][0], 0, 0, 0);
        acc[0][1] = __builtin_amdgcn_mfma_f32_16x16x32_bf16(af0, bf1, acc[0][1], 0, 0, 0);
        acc[1][0] = __builtin_amdgcn_mfma_f32_16x16x32_bf16(af1, bf0, acc[1][0], 0, 0, 0);
        acc[1][1] = __builtin_amdgcn_mfma_f32_16x16x32_bf16(af1, bf1, acc[1][1], 0, 0, 0);
      }
    }
    if (ks + 1 < KSTEPS) __syncthreads();
    if (ks + 2 < KSTEPS) { rA0 = pA0; rA1 = pA1; }
  }

  // ---- per-row inverse norm: reduce over the 8 segment-owner lanes
  ssq += __shfl_xor(ssq, 1, 64);
  ssq += __shfl_xor(ssq, 2, 64);
  ssq += __shfl_xor(ssq, 4, 64);
  // buffer 0's A-region is dead (last read ks=14, barrier'd at end of ks=14)
  float* invx = (float*)lds_raw;
  if (aseg == 0) invx[ar] = 1.f / fmaxf(sqrtf(ssq), CLAMP_EPS);
  __syncthreads();

  // ---- epilogue: C/D layout col=lane&15, row=(lane>>4)*4+reg
  #pragma unroll
  for (int fm = 0; fm < 2; ++fm) {
    #pragma unroll
    for (int r = 0; r < 4; ++r) {
      const int rl = wm * 32 + fm * 16 + (lane >> 4) * 4 + r;
      const float inv = invx[rl];
      float* orow = out + (size_t)(row0 + rl) * KC + col0 + wn * 32 + fr;
      #pragma unroll
      for (int fn = 0; fn < 2; ++fn)
        orow[fn * 16] = fmaf(acc[fm][fn][r] * inv, 0.5f, 0.5f);
    }
  }
}

extern "C" void kernel_launch(void* const* d_in, const int* in_sizes, int n_in,
                              void* d_out, int out_size, void* d_ws, size_t ws_size,
                              hipStream_t stream) {
  const float* x = (const float*)d_in[0];
  const float* c = (const float*)d_in[1];
  float* out = (float*)d_out;
  short* cn = (short*)d_ws;              // 256*1024 bf16 = 512 KB

  const int nrows = in_sizes[0] / DD;    // 32768
  center_norm_kernel<<<KC, 64, 0, stream>>>(c, cn);
  cossim_gemm_kernel<<<(nrows / BM) * (KC / BN), 512, 0, stream>>>(x, cn, out);
}

// Round 8
// 39.687 us; speedup vs baseline: 1.1143x; 1.1143x over previous
//
#include <hip/hip_runtime.h>
#include <hip/hip_bf16.h>

typedef __attribute__((ext_vector_type(8))) short bf16x8;
typedef __attribute__((ext_vector_type(4))) float f32x4;
typedef __attribute__((ext_vector_type(4))) unsigned int u32x4;

#define DD 1024
#define KC 256
#define BM 64
#define BK 64
#define KSTEPS (DD / BK)      // 16
#define BUF_BYTES 40960       // As (8KB) + Bs (32KB) per buffer
#define CLAMP_EPS 1e-8f

__device__ __forceinline__ unsigned short f2bf(float f) {
  unsigned int u = __float_as_uint(f);
  u += 0x7FFFu + ((u >> 16) & 1u);   // RNE
  return (unsigned short)(u >> 16);
}

__device__ __forceinline__ unsigned int pk2(float x, float y) {
  __hip_bfloat162 h = __float22bfloat162_rn(float2{x, y});
  return *reinterpret_cast<unsigned int*>(&h);
}

__device__ __forceinline__ bf16x8 cvt8(f32x4 lo, f32x4 hi) {
  u32x4 w;
  w[0] = pk2(lo[0], lo[1]);
  w[1] = pk2(lo[2], lo[3]);
  w[2] = pk2(hi[0], hi[1]);
  w[3] = pk2(hi[2], hi[3]);
  return __builtin_bit_cast(bf16x8, w);
}

// async global->LDS, 16B per lane; LDS dest is wave-uniform base + lane*16
__device__ __forceinline__ void gload_lds16(const short* g, short* l) {
  __builtin_amdgcn_global_load_lds(
      (__attribute__((address_space(1))) void*)g,
      (__attribute__((address_space(3))) void*)l, 16, 0, 0);
}

// Kernel 1: per-center inverse-norm + prenormalized bf16 copy into ws.
__global__ __launch_bounds__(64) void center_norm_kernel(
    const float* __restrict__ c, short* __restrict__ cn) {
  const int k = blockIdx.x;
  const int lane = threadIdx.x;
  const float* row = c + (size_t)k * DD + lane * 16;
  f32x4 v0 = *(const f32x4*)(row);
  f32x4 v1 = *(const f32x4*)(row + 4);
  f32x4 v2 = *(const f32x4*)(row + 8);
  f32x4 v3 = *(const f32x4*)(row + 12);
  float ss = 0.f;
  #pragma unroll
  for (int j = 0; j < 4; ++j)
    ss += v0[j]*v0[j] + v1[j]*v1[j] + v2[j]*v2[j] + v3[j]*v3[j];
  #pragma unroll
  for (int off = 32; off > 0; off >>= 1) ss += __shfl_xor(ss, off, 64);
  const float inv = 1.f / fmaxf(sqrtf(ss), CLAMP_EPS);
  bf16x8 lo, hi;
  #pragma unroll
  for (int j = 0; j < 4; ++j) {
    lo[j]     = (short)f2bf(v0[j] * inv);
    lo[j + 4] = (short)f2bf(v1[j] * inv);
    hi[j]     = (short)f2bf(v2[j] * inv);
    hi[j + 4] = (short)f2bf(v3[j] * inv);
  }
  short* o = cn + (size_t)k * DD + lane * 16;
  *(bf16x8*)o = lo;
  *(bf16x8*)(o + 8) = hi;
}

// Kernel 2: fused cosine-sim GEMM, double-buffered LDS (R3 base).
// R8 deltas: (a) A cvt+ds_write moved AFTER compute -> A-load lead ~2 windows;
// (b) fused-asm counted barrier "vmcnt(2) lgkmcnt(0); s_barrier" keeps the
// 2 A-prefetch loads in flight across the barrier; (c) single sched_barrier
// pins B-gloads (oldest) before A-loads in the vmem queue.
__global__ __launch_bounds__(512, 4) void cossim_gemm_kernel(
    const float* __restrict__ x, const short* __restrict__ cn,
    float* __restrict__ out) {
  __shared__ __align__(16) char lds_raw[2 * BUF_BYTES];   // 80 KB

  const int t = threadIdx.x;
  const int lane = t & 63;
  const int wid = t >> 6;
  const int wm = wid >> 2;     // 0..1
  const int wn = wid & 3;      // 0..3
  const int fr = lane & 15;
  const int row0 = blockIdx.x * BM;

  // ---- A staging geometry: thread owns (row ar, 8-float segment aseg)
  const int ar = t >> 3;
  const int aseg = t & 7;
  const float* aptr = x + (size_t)(row0 + ar) * DD + aseg * 8;
  const int sA = (ar * BK + aseg * 8) ^ ((ar & 7) << 3);   // swizzled, shorts

  // ---- B staging via gload_lds: pre-swizzled source, linear LDS dest
  const short* bsrc0; const short* bsrc1; const short* bsrc2; const short* bsrc3;
  int bld0, bld1, bld2, bld3;
  {
    #define BGEO(i, PS, PL) {                       \
      const int g = (wid * 4 + (i)) * 64 + lane;    \
      const int n = g >> 3;                         \
      const int cp = (g & 7) ^ (n & 7);             \
      PS = cn + n * DD + cp * 8;                    \
      PL = (wid * 4 + (i)) * 512; }
    BGEO(0, bsrc0, bld0) BGEO(1, bsrc1, bld1)
    BGEO(2, bsrc2, bld2) BGEO(3, bsrc3, bld3)
    #undef BGEO
  }

  float ssq = 0.f;

  // ---- prologue: A(0) sync-ish, B(0) gloads, stage A(0), prefetch A(1)
  f32x4 rA0 = *(const f32x4*)(aptr);          // A(0), consumed below
  f32x4 rA1 = *(const f32x4*)(aptr + 4);
  {
    short* bsb = (short*)(lds_raw + 8192);
    gload_lds16(bsrc0, bsb + bld0);
    gload_lds16(bsrc1, bsb + bld1);
    gload_lds16(bsrc2, bsb + bld2);
    gload_lds16(bsrc3, bsb + bld3);
  }
  __builtin_amdgcn_sched_barrier(0);          // B(0) before A(1) in vmem queue
  f32x4 nA0 = *(const f32x4*)(aptr + BK);     // A(1), spans prologue barrier
  f32x4 nA1 = *(const f32x4*)(aptr + BK + 4);
  #pragma unroll
  for (int j = 0; j < 4; ++j) {
    ssq = fmaf(rA0[j], rA0[j], ssq);
    ssq = fmaf(rA1[j], rA1[j], ssq);
  }
  *(bf16x8*)&((short*)lds_raw)[sA] = cvt8(rA0, rA1);
  asm volatile("s_waitcnt vmcnt(2) lgkmcnt(0)\n\ts_barrier" ::: "memory");
  rA0 = nA0; rA1 = nA1;                       // rA now holds A(1)

  f32x4 acc[2][4];
  #pragma unroll
  for (int i = 0; i < 2; ++i)
    #pragma unroll
    for (int j = 0; j < 4; ++j) acc[i][j] = (f32x4)(0.f);

  #pragma unroll
  for (int ks = 0; ks < KSTEPS; ++ks) {
    const int cb = ks & 1;
    const int nb = cb ^ 1;
    // ---- 1. issue B gloads for tile ks+1 (oldest vmem of this window)
    if (ks + 1 < KSTEPS) {
      short* bsb = (short*)(lds_raw + nb * BUF_BYTES + 8192);
      gload_lds16(bsrc0 + (ks + 1) * BK, bsb + bld0);
      gload_lds16(bsrc1 + (ks + 1) * BK, bsb + bld1);
      gload_lds16(bsrc2 + (ks + 1) * BK, bsb + bld2);
      gload_lds16(bsrc3 + (ks + 1) * BK, bsb + bld3);
      __builtin_amdgcn_sched_barrier(0);   // pin: B gloads precede A loads
    }
    // ---- 2. issue A reg loads for tile ks+2 (newest; span the barrier)
    f32x4 pA0, pA1;
    if (ks + 2 < KSTEPS) {
      pA0 = *(const f32x4*)(aptr + (ks + 2) * BK);
      pA1 = *(const f32x4*)(aptr + (ks + 2) * BK + 4);
    }
    // ---- 3. compute tile ks from buffer cb
    {
      const short* asb = (const short*)(lds_raw + cb * BUF_BYTES);
      const short* bsb = (const short*)(lds_raw + cb * BUF_BYTES + 8192);
      const int swz = (fr & 7) << 3;
      #pragma unroll
      for (int ksub = 0; ksub < 2; ++ksub) {
        const int kk = ksub * 32 + (lane >> 4) * 8;
        bf16x8 af0 = *(const bf16x8*)&asb[((wm * 32 + fr) * BK + kk) ^ swz];
        bf16x8 af1 = *(const bf16x8*)&asb[((wm * 32 + 16 + fr) * BK + kk) ^ swz];
        bf16x8 bf0 = *(const bf16x8*)&bsb[((wn * 64 + fr) * BK + kk) ^ swz];
        bf16x8 bf1 = *(const bf16x8*)&bsb[((wn * 64 + 16 + fr) * BK + kk) ^ swz];
        bf16x8 bf2 = *(const bf16x8*)&bsb[((wn * 64 + 32 + fr) * BK + kk) ^ swz];
        bf16x8 bf3 = *(const bf16x8*)&bsb[((wn * 64 + 48 + fr) * BK + kk) ^ swz];
        acc[0][0] = __builtin_amdgcn_mfma_f32_16x16x32_bf16(af0, bf0, acc[0][0], 0, 0, 0);
        acc[0][1] = __builtin_amdgcn_mfma_f32_16x16x32_bf16(af0, bf1, acc[0][1], 0, 0, 0);
        acc[0][2] = __builtin_amdgcn_mfma_f32_16x16x32_bf16(af0, bf2, acc[0][2], 0, 0, 0);
        acc[0][3] = __builtin_amdgcn_mfma_f32_16x16x32_bf16(af0, bf3, acc[0][3], 0, 0, 0);
        acc[1][0] = __builtin_amdgcn_mfma_f32_16x16x32_bf16(af1, bf0, acc[1][0], 0, 0, 0);
        acc[1][1] = __builtin_amdgcn_mfma_f32_16x16x32_bf16(af1, bf1, acc[1][1], 0, 0, 0);
        acc[1][2] = __builtin_amdgcn_mfma_f32_16x16x32_bf16(af1, bf2, acc[1][2], 0, 0, 0);
        acc[1][3] = __builtin_amdgcn_mfma_f32_16x16x32_bf16(af1, bf3, acc[1][3], 0, 0, 0);
      }
    }
    // ---- 4. ssq + cvt + ds_write of tile ks+1 (A consumed LATE -> long lead)
    if (ks + 1 < KSTEPS) {
      #pragma unroll
      for (int j = 0; j < 4; ++j) {
        ssq = fmaf(rA0[j], rA0[j], ssq);
        ssq = fmaf(rA1[j], rA1[j], ssq);
      }
      short* asb = (short*)(lds_raw + nb * BUF_BYTES);
      *(bf16x8*)&asb[sA] = cvt8(rA0, rA1);
      // ---- 5. counted barrier: B(ks+1) gloads confirmed, A(ks+2) in flight
      if (ks + 2 < KSTEPS) {
        asm volatile("s_waitcnt vmcnt(2) lgkmcnt(0)\n\ts_barrier" ::: "memory");
      } else {
        asm volatile("s_waitcnt vmcnt(0) lgkmcnt(0)\n\ts_barrier" ::: "memory");
      }
    }
    if (ks + 2 < KSTEPS) { rA0 = pA0; rA1 = pA1; }
  }

  // ---- per-row inverse norm: reduce over the 8 segment-owner lanes
  ssq += __shfl_xor(ssq, 1, 64);
  ssq += __shfl_xor(ssq, 2, 64);
  ssq += __shfl_xor(ssq, 4, 64);
  float* invx = (float*)lds_raw;           // reuse As0 (no readers left)
  __syncthreads();
  if (aseg == 0) invx[ar] = 1.f / fmaxf(sqrtf(ssq), CLAMP_EPS);
  __syncthreads();

  // ---- epilogue: C/D layout col=lane&15, row=(lane>>4)*4+reg
  #pragma unroll
  for (int fm = 0; fm < 2; ++fm) {
    #pragma unroll
    for (int r = 0; r < 4; ++r) {
      const int rl = wm * 32 + fm * 16 + (lane >> 4) * 4 + r;
      const float inv = invx[rl];
      float* orow = out + (size_t)(row0 + rl) * KC + wn * 64 + fr;
      #pragma unroll
      for (int fn = 0; fn < 4; ++fn)
        orow[fn * 16] = fmaf(acc[fm][fn][r] * inv, 0.5f, 0.5f);
    }
  }
}

extern "C" void kernel_launch(void* const* d_in, const int* in_sizes, int n_in,
                              void* d_out, int out_size, void* d_ws, size_t ws_size,
                              hipStream_t stream) {
  const float* x = (const float*)d_in[0];
  const float* c = (const float*)d_in[1];
  float* out = (float*)d_out;
  short* cn = (short*)d_ws;              // 256*1024 bf16 = 512 KB

  const int nrows = in_sizes[0] / DD;    // 32768
  center_norm_kernel<<<KC, 64, 0, stream>>>(c, cn);
  cossim_gemm_kernel<<<nrows / BM, 512, 0, stream>>>(x, cn, out);
}

// Round 9
// 38.164 us; speedup vs baseline: 1.1587x; 1.0399x over previous
//
#include <hip/hip_runtime.h>
#include <hip/hip_bf16.h>

typedef __attribute__((ext_vector_type(8))) short bf16x8;
typedef __attribute__((ext_vector_type(4))) float f32x4;
typedef __attribute__((ext_vector_type(4))) unsigned int u32x4;

#define DD 1024
#define KC 256
#define BM 64
#define BK 64
#define KSTEPS (DD / BK)      // 16
#define BUF_BYTES 40960       // As (8KB) + Bs (32KB) per buffer
#define CLAMP_EPS 1e-8f

__device__ __forceinline__ unsigned short f2bf(float f) {
  unsigned int u = __float_as_uint(f);
  u += 0x7FFFu + ((u >> 16) & 1u);   // RNE
  return (unsigned short)(u >> 16);
}

__device__ __forceinline__ unsigned int pk2(float x, float y) {
  __hip_bfloat162 h = __float22bfloat162_rn(float2{x, y});
  return *reinterpret_cast<unsigned int*>(&h);
}

__device__ __forceinline__ bf16x8 cvt8(f32x4 lo, f32x4 hi) {
  u32x4 w;
  w[0] = pk2(lo[0], lo[1]);
  w[1] = pk2(lo[2], lo[3]);
  w[2] = pk2(hi[0], hi[1]);
  w[3] = pk2(hi[2], hi[3]);
  return __builtin_bit_cast(bf16x8, w);
}

// async global->LDS, 16B per lane; LDS dest is wave-uniform base + lane*16
__device__ __forceinline__ void gload_lds16(const short* g, short* l) {
  __builtin_amdgcn_global_load_lds(
      (__attribute__((address_space(1))) void*)g,
      (__attribute__((address_space(3))) void*)l, 16, 0, 0);
}

// Kernel 1: per-center inverse-norm + prenormalized bf16 copy into ws.
__global__ __launch_bounds__(64) void center_norm_kernel(
    const float* __restrict__ c, short* __restrict__ cn) {
  const int k = blockIdx.x;
  const int lane = threadIdx.x;
  const float* row = c + (size_t)k * DD + lane * 16;
  f32x4 v0 = *(const f32x4*)(row);
  f32x4 v1 = *(const f32x4*)(row + 4);
  f32x4 v2 = *(const f32x4*)(row + 8);
  f32x4 v3 = *(const f32x4*)(row + 12);
  float ss = 0.f;
  #pragma unroll
  for (int j = 0; j < 4; ++j)
    ss += v0[j]*v0[j] + v1[j]*v1[j] + v2[j]*v2[j] + v3[j]*v3[j];
  #pragma unroll
  for (int off = 32; off > 0; off >>= 1) ss += __shfl_xor(ss, off, 64);
  const float inv = 1.f / fmaxf(sqrtf(ss), CLAMP_EPS);
  bf16x8 lo, hi;
  #pragma unroll
  for (int j = 0; j < 4; ++j) {
    lo[j]     = (short)f2bf(v0[j] * inv);
    lo[j + 4] = (short)f2bf(v1[j] * inv);
    hi[j]     = (short)f2bf(v2[j] * inv);
    hi[j + 4] = (short)f2bf(v3[j] * inv);
  }
  short* o = cn + (size_t)k * DD + lane * 16;
  *(bf16x8*)o = lo;
  *(bf16x8*)(o + 8) = hi;
}

// Kernel 2: fused cosine-sim GEMM, double-buffered LDS, 1 barrier per K-step.
// R3 structure verbatim (proven best: 37.4us). Only delta: the redundant
// pre-epilogue __syncthreads removed (buffer-0 A reads retired at the
// ks=14 barrier; window-15 reads buffer 1 only).
__global__ __launch_bounds__(512, 4) void cossim_gemm_kernel(
    const float* __restrict__ x, const short* __restrict__ cn,
    float* __restrict__ out) {
  __shared__ __align__(16) char lds_raw[2 * BUF_BYTES];   // 80 KB

  const int t = threadIdx.x;
  const int lane = t & 63;
  const int wid = t >> 6;
  const int wm = wid >> 2;     // 0..1
  const int wn = wid & 3;      // 0..3
  const int fr = lane & 15;
  const int row0 = blockIdx.x * BM;

  // ---- A staging geometry: thread owns (row ar, 8-float segment aseg)
  const int ar = t >> 3;
  const int aseg = t & 7;
  const float* aptr = x + (size_t)(row0 + ar) * DD + aseg * 8;
  const int sA = (ar * BK + aseg * 8) ^ ((ar & 7) << 3);   // swizzled, shorts

  // ---- B staging via gload_lds: pre-swizzled source, linear LDS dest
  const short* bsrc0; const short* bsrc1; const short* bsrc2; const short* bsrc3;
  int bld0, bld1, bld2, bld3;
  {
    #define BGEO(i, PS, PL) {                       \
      const int g = (wid * 4 + (i)) * 64 + lane;    \
      const int n = g >> 3;                         \
      const int cp = (g & 7) ^ (n & 7);             \
      PS = cn + n * DD + cp * 8;                    \
      PL = (wid * 4 + (i)) * 512; }
    BGEO(0, bsrc0, bld0) BGEO(1, bsrc1, bld1)
    BGEO(2, bsrc2, bld2) BGEO(3, bsrc3, bld3)
    #undef BGEO
  }

  float ssq = 0.f;

  // ---- prologue: stage tile 0 into buffer 0, prefetch A tile 1
  f32x4 rA0 = *(const f32x4*)(aptr);
  f32x4 rA1 = *(const f32x4*)(aptr + 4);
  {
    short* bsb = (short*)(lds_raw + 8192);
    gload_lds16(bsrc0, bsb + bld0);
    gload_lds16(bsrc1, bsb + bld1);
    gload_lds16(bsrc2, bsb + bld2);
    gload_lds16(bsrc3, bsb + bld3);
  }
  #pragma unroll
  for (int j = 0; j < 4; ++j) {
    ssq = fmaf(rA0[j], rA0[j], ssq);
    ssq = fmaf(rA1[j], rA1[j], ssq);
  }
  *(bf16x8*)&((short*)lds_raw)[sA] = cvt8(rA0, rA1);
  rA0 = *(const f32x4*)(aptr + BK);
  rA1 = *(const f32x4*)(aptr + BK + 4);
  __syncthreads();

  f32x4 acc[2][4];
  #pragma unroll
  for (int i = 0; i < 2; ++i)
    #pragma unroll
    for (int j = 0; j < 4; ++j) acc[i][j] = (f32x4)(0.f);

  #pragma unroll
  for (int ks = 0; ks < KSTEPS; ++ks) {
    const int cb = ks & 1;
    const int nb = cb ^ 1;
    // ---- 1. issue B gloads for tile ks+1
    if (ks + 1 < KSTEPS) {
      short* bsb = (short*)(lds_raw + nb * BUF_BYTES + 8192);
      gload_lds16(bsrc0 + (ks + 1) * BK, bsb + bld0);
      gload_lds16(bsrc1 + (ks + 1) * BK, bsb + bld1);
      gload_lds16(bsrc2 + (ks + 1) * BK, bsb + bld2);
      gload_lds16(bsrc3 + (ks + 1) * BK, bsb + bld3);
    }
    // ---- 2. issue A reg loads for tile ks+2
    f32x4 pA0, pA1;
    if (ks + 2 < KSTEPS) {
      pA0 = *(const f32x4*)(aptr + (ks + 2) * BK);
      pA1 = *(const f32x4*)(aptr + (ks + 2) * BK + 4);
    }
    // ---- 3. ssq + cvt + ds_write of tile ks+1 from regs
    if (ks + 1 < KSTEPS) {
      #pragma unroll
      for (int j = 0; j < 4; ++j) {
        ssq = fmaf(rA0[j], rA0[j], ssq);
        ssq = fmaf(rA1[j], rA1[j], ssq);
      }
      short* asb = (short*)(lds_raw + nb * BUF_BYTES);
      *(bf16x8*)&asb[sA] = cvt8(rA0, rA1);
    }
    // ---- 4. compute tile ks from buffer cb
    {
      const short* asb = (const short*)(lds_raw + cb * BUF_BYTES);
      const short* bsb = (const short*)(lds_raw + cb * BUF_BYTES + 8192);
      const int swz = (fr & 7) << 3;
      #pragma unroll
      for (int ksub = 0; ksub < 2; ++ksub) {
        const int kk = ksub * 32 + (lane >> 4) * 8;
        bf16x8 af0 = *(const bf16x8*)&asb[((wm * 32 + fr) * BK + kk) ^ swz];
        bf16x8 af1 = *(const bf16x8*)&asb[((wm * 32 + 16 + fr) * BK + kk) ^ swz];
        bf16x8 bf0 = *(const bf16x8*)&bsb[((wn * 64 + fr) * BK + kk) ^ swz];
        bf16x8 bf1 = *(const bf16x8*)&bsb[((wn * 64 + 16 + fr) * BK + kk) ^ swz];
        bf16x8 bf2 = *(const bf16x8*)&bsb[((wn * 64 + 32 + fr) * BK + kk) ^ swz];
        bf16x8 bf3 = *(const bf16x8*)&bsb[((wn * 64 + 48 + fr) * BK + kk) ^ swz];
        acc[0][0] = __builtin_amdgcn_mfma_f32_16x16x32_bf16(af0, bf0, acc[0][0], 0, 0, 0);
        acc[0][1] = __builtin_amdgcn_mfma_f32_16x16x32_bf16(af0, bf1, acc[0][1], 0, 0, 0);
        acc[0][2] = __builtin_amdgcn_mfma_f32_16x16x32_bf16(af0, bf2, acc[0][2], 0, 0, 0);
        acc[0][3] = __builtin_amdgcn_mfma_f32_16x16x32_bf16(af0, bf3, acc[0][3], 0, 0, 0);
        acc[1][0] = __builtin_amdgcn_mfma_f32_16x16x32_bf16(af1, bf0, acc[1][0], 0, 0, 0);
        acc[1][1] = __builtin_amdgcn_mfma_f32_16x16x32_bf16(af1, bf1, acc[1][1], 0, 0, 0);
        acc[1][2] = __builtin_amdgcn_mfma_f32_16x16x32_bf16(af1, bf2, acc[1][2], 0, 0, 0);
        acc[1][3] = __builtin_amdgcn_mfma_f32_16x16x32_bf16(af1, bf3, acc[1][3], 0, 0, 0);
      }
    }
    if (ks + 1 < KSTEPS) __syncthreads();
    if (ks + 2 < KSTEPS) { rA0 = pA0; rA1 = pA1; }
  }

  // ---- per-row inverse norm: reduce over the 8 segment-owner lanes
  ssq += __shfl_xor(ssq, 1, 64);
  ssq += __shfl_xor(ssq, 2, 64);
  ssq += __shfl_xor(ssq, 4, 64);
  // buffer-0 A region is dead (its reads retired at the ks=14 barrier;
  // window 15 reads buffer 1) -> write invx without a preceding barrier
  float* invx = (float*)lds_raw;
  if (aseg == 0) invx[ar] = 1.f / fmaxf(sqrtf(ssq), CLAMP_EPS);
  __syncthreads();

  // ---- epilogue: C/D layout col=lane&15, row=(lane>>4)*4+reg
  #pragma unroll
  for (int fm = 0; fm < 2; ++fm) {
    #pragma unroll
    for (int r = 0; r < 4; ++r) {
      const int rl = wm * 32 + fm * 16 + (lane >> 4) * 4 + r;
      const float inv = invx[rl];
      float* orow = out + (size_t)(row0 + rl) * KC + wn * 64 + fr;
      #pragma unroll
      for (int fn = 0; fn < 4; ++fn)
        orow[fn * 16] = fmaf(acc[fm][fn][r] * inv, 0.5f, 0.5f);
    }
  }
}

extern "C" void kernel_launch(void* const* d_in, const int* in_sizes, int n_in,
                              void* d_out, int out_size, void* d_ws, size_t ws_size,
                              hipStream_t stream) {
  const float* x = (const float*)d_in[0];
  const float* c = (const float*)d_in[1];
  float* out = (float*)d_out;
  short* cn = (short*)d_ws;              // 256*1024 bf16 = 512 KB

  const int nrows = in_sizes[0] / DD;    // 32768
  center_norm_kernel<<<KC, 64, 0, stream>>>(c, cn);
  cossim_gemm_kernel<<<nrows / BM, 512, 0, stream>>>(x, cn, out);
}